// Round 2
// baseline (607.974 us; speedup 1.0000x reference)
//
#include <hip/hip_runtime.h>

constexpr int NN  = 100000;   // nodes
constexpr int NE  = 1600000;  // edges
constexpr int HID = 32;

// ---------------- kernels ----------------

// count in-degree (edges only; +1 self-loop added analytically later)
__global__ __launch_bounds__(256) void k_count(const int* __restrict__ ei,
                                               float* __restrict__ deg) {
  int e = blockIdx.x * 256 + threadIdx.x;
  if (e < NE) atomicAdd(&deg[ei[NE + e]], 1.0f);
}

// dinv = rsqrt(deg+1); init agg1 with self-loop term x[i]*dinv^2
__global__ __launch_bounds__(256) void k_dinv(const float* __restrict__ deg,
                                              const float* __restrict__ x,
                                              float* __restrict__ dinv,
                                              float* __restrict__ agg1) {
  int i = blockIdx.x * 256 + threadIdx.x;
  if (i >= NN) return;
  float dg = deg[i] + 1.0f;
  float di = rsqrtf(dg);
  dinv[i] = di;
  float d2 = di * di;
  agg1[2 * i]     = x[2 * i]     * d2;
  agg1[2 * i + 1] = x[2 * i + 1] * d2;
}

// layer-1 aggregation of raw 2-feature x; also materialize per-edge norm
__global__ __launch_bounds__(256) void k_l1agg(const int* __restrict__ ei,
                                               const float* __restrict__ dinv,
                                               const float* __restrict__ x,
                                               float* __restrict__ norm,
                                               float* __restrict__ agg1) {
  int e = blockIdx.x * 256 + threadIdx.x;
  if (e >= NE) return;
  int s = ei[e], d = ei[NE + e];
  float nr = dinv[s] * dinv[d];
  norm[e] = nr;
  atomicAdd(&agg1[2 * d],     x[2 * s]     * nr);
  atomicAdd(&agg1[2 * d + 1], x[2 * s + 1] * nr);
}

// per-node: h1 = relu(LN(agg1 @ w1 + b1)); also pre-init agg2 with self term
__global__ __launch_bounds__(256) void k_l1node(const float* __restrict__ agg1,
                                                const float* __restrict__ dinv,
                                                const float* __restrict__ w1,
                                                const float* __restrict__ b1,
                                                const float* __restrict__ g1,
                                                const float* __restrict__ be1,
                                                float* __restrict__ h1,
                                                float* __restrict__ agg2) {
  __shared__ float w1s[64], b1s[32], g1s[32], be1s[32];
  int t = threadIdx.x;
  if (t < 64) w1s[t] = w1[t];
  if (t < 32) { b1s[t] = b1[t]; g1s[t] = g1[t]; be1s[t] = be1[t]; }
  __syncthreads();
  int i = blockIdx.x * 256 + t;
  if (i >= NN) return;
  float a0 = agg1[2 * i], a1 = agg1[2 * i + 1];
  float h[HID];
  float mu = 0.f;
#pragma unroll
  for (int j = 0; j < HID; j++) {
    h[j] = fmaf(a0, w1s[j], fmaf(a1, w1s[32 + j], b1s[j]));
    mu += h[j];
  }
  mu *= (1.0f / HID);
  float var = 0.f;
#pragma unroll
  for (int j = 0; j < HID; j++) { float dd = h[j] - mu; var += dd * dd; }
  var *= (1.0f / HID);
  float rstd = rsqrtf(var + 1e-5f);
  float di = dinv[i];
  float d2 = di * di;
#pragma unroll
  for (int j = 0; j < HID; j++) {
    float v = fmaf((h[j] - mu) * rstd, g1s[j], be1s[j]);
    v = fmaxf(v, 0.0f);
    h1[(size_t)i * HID + j]   = v;
    agg2[(size_t)i * HID + j] = v * d2;   // self-loop contribution for layer 2
  }
}

// layer-2 aggregation: 32 lanes = 32 features of one edge
__global__ __launch_bounds__(256) void k_l2agg(const int* __restrict__ ei,
                                               const float* __restrict__ norm,
                                               const float* __restrict__ h1,
                                               float* __restrict__ agg2) {
  long long t = (long long)blockIdx.x * 256 + threadIdx.x;
  int e = (int)(t >> 5), f = (int)(t & 31);
  if (e >= NE) return;
  int s = ei[e], d = ei[NE + e];
  float v = h1[(size_t)s * HID + f] * norm[e];
  atomicAdd(&agg2[(size_t)d * HID + f], v);
}

// per-node: h2 = relu(LN(agg2 @ w2 + b2)); p = h2 @ w3; out init = self + b3
__global__ __launch_bounds__(256) void k_l2node(const float* __restrict__ agg2,
                                                const float* __restrict__ dinv,
                                                const float* __restrict__ w2,
                                                const float* __restrict__ b2,
                                                const float* __restrict__ g2,
                                                const float* __restrict__ be2,
                                                const float* __restrict__ w3,
                                                const float* __restrict__ b3,
                                                float* __restrict__ p,
                                                float* __restrict__ out) {
  __shared__ float w2t[HID * HID];  // transposed: w2t[j][k] = w2[k][j]
  __shared__ float b2s[32], g2s[32], be2s[32], w3s[32];
  __shared__ float b3s;
  int t = threadIdx.x;
  for (int u = t; u < HID * HID; u += 256) {
    int k = u >> 5, j = u & 31;           // u = k*32 + j
    w2t[j * HID + k] = w2[u];
  }
  if (t < 32) { b2s[t] = b2[t]; g2s[t] = g2[t]; be2s[t] = be2[t]; w3s[t] = w3[t]; }
  if (t == 0) b3s = b3[0];
  __syncthreads();
  int i = blockIdx.x * 256 + t;
  if (i >= NN) return;
  float a[HID];
  const float4* ag4 = (const float4*)(agg2 + (size_t)i * HID);
#pragma unroll
  for (int q = 0; q < 8; q++) {
    float4 v = ag4[q];
    a[4 * q] = v.x; a[4 * q + 1] = v.y; a[4 * q + 2] = v.z; a[4 * q + 3] = v.w;
  }
  float h[HID];
  float mu = 0.f;
#pragma unroll
  for (int j = 0; j < HID; j++) {
    float acc = b2s[j];
#pragma unroll
    for (int k = 0; k < HID; k++) acc = fmaf(a[k], w2t[j * HID + k], acc);
    h[j] = acc;
    mu += acc;
  }
  mu *= (1.0f / HID);
  float var = 0.f;
#pragma unroll
  for (int j = 0; j < HID; j++) { float dd = h[j] - mu; var += dd * dd; }
  var *= (1.0f / HID);
  float rstd = rsqrtf(var + 1e-5f);
  float pi = 0.f;
#pragma unroll
  for (int j = 0; j < HID; j++) {
    float v = fmaf((h[j] - mu) * rstd, g2s[j], be2s[j]);
    v = fmaxf(v, 0.0f);
    pi = fmaf(v, w3s[j], pi);
  }
  p[i] = pi;
  float di = dinv[i];
  out[i] = fmaf(pi, di * di, b3s);  // self-loop + bias; edges atomically added next
}

// layer-3 aggregation: 1 feature per edge
__global__ __launch_bounds__(256) void k_l3agg(const int* __restrict__ ei,
                                               const float* __restrict__ norm,
                                               const float* __restrict__ p,
                                               float* __restrict__ out) {
  int e = blockIdx.x * 256 + threadIdx.x;
  if (e >= NE) return;
  atomicAdd(&out[ei[NE + e]], p[ei[e]] * norm[e]);
}

// ---------------- launch ----------------

extern "C" void kernel_launch(void* const* d_in, const int* in_sizes, int n_in,
                              void* d_out, int out_size, void* d_ws, size_t ws_size,
                              hipStream_t stream) {
  const float* x   = (const float*)d_in[0];
  const int*   ei  = (const int*)d_in[1];
  const float* w1  = (const float*)d_in[2];
  const float* b1  = (const float*)d_in[3];
  const float* g1  = (const float*)d_in[4];
  const float* be1 = (const float*)d_in[5];
  const float* w2  = (const float*)d_in[6];
  const float* b2  = (const float*)d_in[7];
  const float* g2  = (const float*)d_in[8];
  const float* be2 = (const float*)d_in[9];
  const float* w3  = (const float*)d_in[10];
  const float* b3  = (const float*)d_in[11];
  float* out = (float*)d_out;

  char* wp = (char*)d_ws;
  auto alloc = [&](size_t bytes) {
    char* r = wp;
    wp += (bytes + 255) & ~size_t(255);
    return r;
  };
  float* norm = (float*)alloc((size_t)NE * 4);
  float* deg  = (float*)alloc((size_t)NN * 4);
  float* dinv = (float*)alloc((size_t)NN * 4);
  float* agg1 = (float*)alloc((size_t)NN * 2 * 4);
  float* h1   = (float*)alloc((size_t)NN * HID * 4);
  float* agg2 = (float*)alloc((size_t)NN * HID * 4);
  float* p    = (float*)alloc((size_t)NN * 4);

  int bn = (NN + 255) / 256;
  int bE = (NE + 255) / 256;
  long long tot32 = (long long)NE * 32;
  int bE32 = (int)((tot32 + 255) / 256);  // 200000 blocks

  hipMemsetAsync(deg, 0, (size_t)NN * 4, stream);
  k_count<<<bE, 256, 0, stream>>>(ei, deg);
  k_dinv<<<bn, 256, 0, stream>>>(deg, x, dinv, agg1);
  k_l1agg<<<bE, 256, 0, stream>>>(ei, dinv, x, norm, agg1);
  k_l1node<<<bn, 256, 0, stream>>>(agg1, dinv, w1, b1, g1, be1, h1, agg2);
  k_l2agg<<<bE32, 256, 0, stream>>>(ei, norm, h1, agg2);
  k_l2node<<<bn, 256, 0, stream>>>(agg2, dinv, w2, b2, g2, be2, w3, b3, p, out);
  k_l3agg<<<bE, 256, 0, stream>>>(ei, norm, p, out);
}

// Round 3
// 432.264 us; speedup vs baseline: 1.4065x; 1.4065x over previous
//
#include <hip/hip_runtime.h>

constexpr int NN  = 100000;   // nodes
constexpr int NE  = 1600000;  // edges
constexpr int HID = 32;
constexpr int NB  = (NN + 255) / 256;   // 391 node-blocks

// ---------------- CSR build ----------------

// in-degree count (edges only; +1 self-loop folded into dinv analytically)
__global__ __launch_bounds__(256) void k_count(const int* __restrict__ ei,
                                               int* __restrict__ deg) {
  int e = blockIdx.x * 256 + threadIdx.x;
  if (e < NE) atomicAdd(&deg[ei[NE + e]], 1);
}

// per-block exclusive scan of deg -> rowptr(local); block totals; dinv
__global__ __launch_bounds__(256) void k_scanA(const int* __restrict__ deg,
                                               int* __restrict__ rowptr,
                                               int* __restrict__ bsum,
                                               float* __restrict__ dinv) {
  __shared__ int s[256];
  int t = threadIdx.x;
  int i = blockIdx.x * 256 + t;
  int v = (i < NN) ? deg[i] : 0;
  if (i < NN) dinv[i] = rsqrtf((float)v + 1.0f);
  s[t] = v;
  __syncthreads();
#pragma unroll
  for (int off = 1; off < 256; off <<= 1) {
    int add = (t >= off) ? s[t - off] : 0;
    __syncthreads();
    s[t] += add;
    __syncthreads();
  }
  if (i < NN) rowptr[i] = s[t] - v;   // exclusive within block
  if (t == 255) bsum[blockIdx.x] = s[255];
}

// single-block exclusive scan of the NB block totals
__global__ __launch_bounds__(512) void k_scanB(int* __restrict__ bsum) {
  __shared__ int s[512];
  int t = threadIdx.x;
  int v = (t < NB) ? bsum[t] : 0;
  s[t] = v;
  __syncthreads();
#pragma unroll
  for (int off = 1; off < 512; off <<= 1) {
    int add = (t >= off) ? s[t - off] : 0;
    __syncthreads();
    s[t] += add;
    __syncthreads();
  }
  if (t < NB) bsum[t] = s[t] - v;     // exclusive
}

// apply block offsets; init scatter cursors
__global__ __launch_bounds__(256) void k_scanC(int* __restrict__ rowptr,
                                               const int* __restrict__ bsum,
                                               int* __restrict__ cursor) {
  int i = blockIdx.x * 256 + threadIdx.x;
  if (i < NN) {
    int r = rowptr[i] + bsum[blockIdx.x];
    rowptr[i] = r;
    cursor[i] = r;
  }
}

// scatter src indices into per-dst contiguous CSR slots
__global__ __launch_bounds__(256) void k_scatter(const int* __restrict__ ei,
                                                 int* __restrict__ cursor,
                                                 int* __restrict__ csr) {
  int e = blockIdx.x * 256 + threadIdx.x;
  if (e >= NE) return;
  int s = ei[e], d = ei[NE + e];
  int pos = atomicAdd(&cursor[d], 1);
  csr[pos] = s;
}

// ---------------- layers ----------------

// layer 1: per-node thread. agg1 = dinv[i]*(dinv[i]*x[i] + sum dinv[s]*x[s]);
// then 2x32 matmul + LN + relu -> h1
__global__ __launch_bounds__(256) void k_l1(const int* __restrict__ rowptr,
                                            const int* __restrict__ deg,
                                            const int* __restrict__ csr,
                                            const float* __restrict__ dinv,
                                            const float* __restrict__ x,
                                            const float* __restrict__ w1,
                                            const float* __restrict__ b1,
                                            const float* __restrict__ g1,
                                            const float* __restrict__ be1,
                                            float* __restrict__ h1) {
  __shared__ float w1s[64], b1s[32], g1s[32], be1s[32];
  int t = threadIdx.x;
  if (t < 64) w1s[t] = w1[t];
  if (t < 32) { b1s[t] = b1[t]; g1s[t] = g1[t]; be1s[t] = be1[t]; }
  __syncthreads();
  int i = blockIdx.x * 256 + t;
  if (i >= NN) return;
  float di = dinv[i];
  const float2* x2 = (const float2*)x;
  float2 xs = x2[i];
  float in0 = di * xs.x, in1 = di * xs.y;
  int r0 = rowptr[i], dg = deg[i];
  for (int k = 0; k < dg; k++) {
    int s = csr[r0 + k];
    float ds = dinv[s];
    float2 xv = x2[s];
    in0 = fmaf(ds, xv.x, in0);
    in1 = fmaf(ds, xv.y, in1);
  }
  float a0 = di * in0, a1 = di * in1;
  float h[HID];
  float mu = 0.f;
#pragma unroll
  for (int j = 0; j < HID; j++) {
    h[j] = fmaf(a0, w1s[j], fmaf(a1, w1s[32 + j], b1s[j]));
    mu += h[j];
  }
  mu *= (1.0f / HID);
  float var = 0.f;
#pragma unroll
  for (int j = 0; j < HID; j++) { float dd = h[j] - mu; var += dd * dd; }
  var *= (1.0f / HID);
  float rstd = rsqrtf(var + 1e-5f);
  float4* o4 = (float4*)(h1 + (size_t)i * HID);
#pragma unroll
  for (int q = 0; q < 8; q++) {
    float4 v;
    v.x = fmaxf(fmaf((h[4 * q]     - mu) * rstd, g1s[4 * q],     be1s[4 * q]),     0.f);
    v.y = fmaxf(fmaf((h[4 * q + 1] - mu) * rstd, g1s[4 * q + 1], be1s[4 * q + 1]), 0.f);
    v.z = fmaxf(fmaf((h[4 * q + 2] - mu) * rstd, g1s[4 * q + 2], be1s[4 * q + 2]), 0.f);
    v.w = fmaxf(fmaf((h[4 * q + 3] - mu) * rstd, g1s[4 * q + 3], be1s[4 * q + 3]), 0.f);
    o4[q] = v;
  }
}

// layer 2 fused: 32 lanes = one node. Register aggregation (no atomics),
// in-register 32x32 matvec via shuffles, LN via xor-reduce, relu, w3 -> p
__global__ __launch_bounds__(256) void k_l2(const int* __restrict__ rowptr,
                                            const int* __restrict__ deg,
                                            const int* __restrict__ csr,
                                            const float* __restrict__ dinv,
                                            const float* __restrict__ h1,
                                            const float* __restrict__ w2,
                                            const float* __restrict__ b2,
                                            const float* __restrict__ g2,
                                            const float* __restrict__ be2,
                                            const float* __restrict__ w3,
                                            float* __restrict__ p) {
  __shared__ float w2s[HID * HID];
  __shared__ float b2s[32], g2s[32], be2s[32], w3s[32];
  int t = threadIdx.x;
  for (int u = t; u < HID * HID; u += 256) w2s[u] = w2[u];
  if (t < 32) { b2s[t] = b2[t]; g2s[t] = g2[t]; be2s[t] = be2[t]; w3s[t] = w3[t]; }
  __syncthreads();
  int i = blockIdx.x * 8 + (t >> 5);   // node
  int f = t & 31;                      // feature lane
  if (i >= NN) return;
  float di = dinv[i];
  // inner = di*h1[i,f] + sum_s dinv[s]*h1[s,f];  agg = di*inner
  float acc = di * h1[(size_t)i * HID + f];
  int r0 = rowptr[i], dg = deg[i];
  for (int k = 0; k < dg; k++) {
    int s = csr[r0 + k];              // broadcast within the 32-lane group
    float ds = dinv[s];
    acc = fmaf(ds, h1[(size_t)s * HID + f], acc);  // 128B coalesced gather
  }
  acc *= di;                           // agg2[i,f]
  // h[f] = b2[f] + sum_k agg2[k] * w2[k,f]
  float h = b2s[f];
#pragma unroll
  for (int k = 0; k < HID; k++) {
    float ak = __shfl(acc, k, 32);
    h = fmaf(ak, w2s[k * HID + f], h);
  }
  // LayerNorm across the 32 lanes
  float mu = h;
#pragma unroll
  for (int off = 16; off > 0; off >>= 1) mu += __shfl_xor(mu, off, 32);
  mu *= (1.0f / HID);
  float dd = h - mu;
  float var = dd * dd;
#pragma unroll
  for (int off = 16; off > 0; off >>= 1) var += __shfl_xor(var, off, 32);
  var *= (1.0f / HID);
  float rstd = rsqrtf(var + 1e-5f);
  float v = fmaf(dd * rstd, g2s[f], be2s[f]);
  v = fmaxf(v, 0.0f);
  float pi = v * w3s[f];
#pragma unroll
  for (int off = 16; off > 0; off >>= 1) pi += __shfl_xor(pi, off, 32);
  if (f == 0) p[i] = pi;
}

// layer 3: per-node thread. out = b3 + di*(di*p[i] + sum dinv[s]*p[s])
__global__ __launch_bounds__(256) void k_l3(const int* __restrict__ rowptr,
                                            const int* __restrict__ deg,
                                            const int* __restrict__ csr,
                                            const float* __restrict__ dinv,
                                            const float* __restrict__ p,
                                            const float* __restrict__ b3,
                                            float* __restrict__ out) {
  int i = blockIdx.x * 256 + threadIdx.x;
  if (i >= NN) return;
  float di = dinv[i];
  float inner = di * p[i];
  int r0 = rowptr[i], dg = deg[i];
  for (int k = 0; k < dg; k++) {
    int s = csr[r0 + k];
    inner = fmaf(dinv[s], p[s], inner);
  }
  out[i] = fmaf(di, inner, b3[0]);
}

// ---------------- launch ----------------

extern "C" void kernel_launch(void* const* d_in, const int* in_sizes, int n_in,
                              void* d_out, int out_size, void* d_ws, size_t ws_size,
                              hipStream_t stream) {
  const float* x   = (const float*)d_in[0];
  const int*   ei  = (const int*)d_in[1];
  const float* w1  = (const float*)d_in[2];
  const float* b1  = (const float*)d_in[3];
  const float* g1  = (const float*)d_in[4];
  const float* be1 = (const float*)d_in[5];
  const float* w2  = (const float*)d_in[6];
  const float* b2  = (const float*)d_in[7];
  const float* g2  = (const float*)d_in[8];
  const float* be2 = (const float*)d_in[9];
  const float* w3  = (const float*)d_in[10];
  const float* b3  = (const float*)d_in[11];
  float* out = (float*)d_out;

  char* wp = (char*)d_ws;
  auto alloc = [&](size_t bytes) {
    char* r = wp;
    wp += (bytes + 255) & ~size_t(255);
    return r;
  };
  int*   deg    = (int*)alloc((size_t)NN * 4);
  int*   rowptr = (int*)alloc((size_t)NN * 4);
  int*   cursor = (int*)alloc((size_t)NN * 4);
  int*   bsum   = (int*)alloc((size_t)NB * 4);
  float* dinv   = (float*)alloc((size_t)NN * 4);
  int*   csr    = (int*)alloc((size_t)NE * 4);
  float* h1     = (float*)alloc((size_t)NN * HID * 4);
  float* p      = (float*)alloc((size_t)NN * 4);

  int bE = (NE + 255) / 256;

  hipMemsetAsync(deg, 0, (size_t)NN * 4, stream);
  k_count  <<<bE, 256, 0, stream>>>(ei, deg);
  k_scanA  <<<NB, 256, 0, stream>>>(deg, rowptr, bsum, dinv);
  k_scanB  <<<1, 512, 0, stream>>>(bsum);
  k_scanC  <<<NB, 256, 0, stream>>>(rowptr, bsum, cursor);
  k_scatter<<<bE, 256, 0, stream>>>(ei, cursor, csr);
  k_l1     <<<NB, 256, 0, stream>>>(rowptr, deg, csr, dinv, x, w1, b1, g1, be1, h1);
  k_l2     <<<(NN + 7) / 8, 256, 0, stream>>>(rowptr, deg, csr, dinv, h1,
                                              w2, b2, g2, be2, w3, p);
  k_l3     <<<NB, 256, 0, stream>>>(rowptr, deg, csr, dinv, p, b3, out);
}